// Round 1
// baseline (194.962 us; speedup 1.0000x reference)
//
#include <hip/hip_runtime.h>
#include <hip/hip_bf16.h>

#define IN_C  128
#define HID_C 128
#define OUT_CC 64
#define BK    128           // nodes per bucket (dst >> 7)
#define CAPLG 12            // bucket capacity 4096 edges (mean 2046, >40 sigma)

using short8  = __attribute__((ext_vector_type(8))) short;
using float4v = __attribute__((ext_vector_type(4))) float;

// fp32 -> bf16 (round-to-nearest-even, finite inputs)
__device__ __forceinline__ unsigned short f2b(float f) {
    unsigned int u = __float_as_uint(f);
    return (unsigned short)((u + 0x7fffu + ((u >> 16) & 1u)) >> 16);
}
__device__ __forceinline__ unsigned int pack2(float a, float b) {
    return (unsigned int)f2b(a) | ((unsigned int)f2b(b) << 16);
}
__device__ __forceinline__ float2 bf2_to_f2(unsigned int v) {
    float2 r;
    r.x = __uint_as_float(v << 16);
    r.y = __uint_as_float(v & 0xffff0000u);
    return r;
}

// ---- ws layout (bytes) ----
// flag      int            @ 0
// bfill     int[391]       @ 64
// begend    int2[N]        @ 4096       (ends 404,096)
// dinv      float[N]       @ 404480     (ends 604,480)
// w1frag    bf16[16384]    @ 604672
// w2frag    bf16[8192]     @ 637440
// ebuf      int[391*4096]  @ 655360     (packed src|dlocal<<20; ends 7,061,504)
// col       int[391*4096]  @ 7061504    (ends 13,467,648)
// h (bf16)  [N*128]        @ 13467904   (pre-scaled by dinv[row]; ends 26,267,904)
// h2(bf16)  [N*64]         @ 26267904   (pre-scaled by dinv[row]; ends 32,667,904)
// deg       int[N]         @ 32668160   (in-degree histogram from k_bpart)

// ---------------- setup: weight prep + edge dtype probe + bfill/deg zero ----------------
__global__ __launch_bounds__(256) void k_setup(const float* __restrict__ W1,
                                               const float* __restrict__ W2,
                                               const int* __restrict__ ei,
                                               unsigned short* __restrict__ w1f,
                                               unsigned short* __restrict__ w2f,
                                               int* __restrict__ flag,
                                               int* __restrict__ bfill,
                                               int* __restrict__ deg, int NBK, int N) {
    int e = blockIdx.x * 256 + threadIdx.x;
    if (e < 16384) {                                  // W1: frag ((nt*4+ks)*64+lane)*8+j
        int j = e & 7, lane = (e >> 3) & 63, ks = (e >> 9) & 3, nt = e >> 11;
        int k = ks * 32 + ((lane >> 4) << 3) + j;
        int n = nt * 16 + (lane & 15);
        w1f[e] = f2b(W1[k * 128 + n]);
    } else if (e < 16384 + 8192) {
        int e2 = e - 16384;
        int j = e2 & 7, lane = (e2 >> 3) & 63, ks = (e2 >> 9) & 3, nt = e2 >> 11;
        int k = ks * 32 + ((lane >> 4) << 3) + j;
        int n = nt * 16 + (lane & 15);
        w2f[e2] = f2b(W2[k * 64 + n]);
    }
    for (int i = e; i < N; i += 96 * 256) deg[i] = 0;  // zero degree histogram
    if (blockIdx.x == 0) {
        for (int i = threadIdx.x; i < NBK; i += 256) bfill[i] = 0;
        if (threadIdx.x == 0) {
            int odd_zero = 1, any_even = 0;
            for (int i = 0; i < 64; ++i) {
                if (ei[2 * i + 1] != 0) odd_zero = 0;
                if (ei[2 * i] != 0) any_even = 1;
            }
            *flag = (odd_zero && any_even) ? 2 : 1;
        }
    }
}

// ---------------- partition edges into fixed-capacity bucket regions ----------------
// ebuf[b<<CAPLG + rank] = src | (dst & 127) << 20 ; also builds deg[] histogram
__global__ __launch_bounds__(256) void k_bpart(const int* __restrict__ ei,
                                               const int* __restrict__ flag,
                                               int* __restrict__ bfill,
                                               int* __restrict__ deg,
                                               int* __restrict__ ebuf, int E, int NBK) {
    __shared__ int lh[512];
    __shared__ int lbase[512];
    const int t = threadIdx.x;
    for (int i = t; i < NBK; i += 256) lh[i] = 0;
    __syncthreads();
    const int st = *flag;
    const int base = blockIdx.x * 2048;
    int s[8], d[8];
    #pragma unroll
    for (int j = 0; j < 8; ++j) {
        int i = base + j * 256 + t;
        if (i < E) {
            s[j] = ei[(size_t)st * i];
            d[j] = ei[(size_t)st * ((size_t)E + i)];
            atomicAdd(&lh[d[j] >> 7], 1);
            atomicAdd(&deg[d[j]], 1);                // global in-degree (for GEMM1 pre-scale)
        } else d[j] = -1;
    }
    __syncthreads();
    for (int i = t; i < NBK; i += 256) {
        int c = lh[i];
        lbase[i] = c ? atomicAdd(&bfill[i], c) : 0;
        lh[i] = 0;                                   // becomes local rank counter
    }
    __syncthreads();
    #pragma unroll
    for (int j = 0; j < 8; ++j) {
        if (d[j] >= 0) {
            int b = d[j] >> 7;
            int r = lbase[b] + atomicAdd(&lh[b], 1);
            if (r < (1 << CAPLG))                    // statistical safety clamp
                ebuf[(b << CAPLG) + r] = s[j] | ((d[j] & (BK - 1)) << 20);
        }
    }
}

// ---------------- fused: per-bucket local CSR (blocks < NBK) | MFMA GEMM1 (rest) ----
// GEMM1 tiles write h pre-scaled by dinv[row] (= rsqrt(deg+1)) so agg needs no per-edge dinv
__global__ __launch_bounds__(256) void k_blmg1(const int* __restrict__ ebuf,
                                               const int* __restrict__ bfill,
                                               int2* __restrict__ begend,
                                               float* __restrict__ dinv,
                                               int* __restrict__ col,
                                               const float* __restrict__ x,
                                               const unsigned short* __restrict__ w1f,
                                               const int* __restrict__ deg,
                                               unsigned short* __restrict__ h,
                                               int N, int NBK) {
    __shared__ unsigned short lds[64 * 136];          // 17.4 KB, shared by both paths
    const int t = threadIdx.x;

    if ((int)blockIdx.x < NBK) {
        // ---- per-bucket CSR build ----
        int* cnt = (int*)lds;
        int* sc  = cnt + BK;
        int* off = sc + BK;
        const int n0 = blockIdx.x * BK;
        const int beg = (int)blockIdx.x << CAPLG;
        const int ecnt = min(bfill[blockIdx.x], 1 << CAPLG);
        if (t < BK) cnt[t] = 0;
        __syncthreads();
        for (int i = t; i < ecnt; i += 256)
            atomicAdd(&cnt[ebuf[beg + i] >> 20], 1);
        __syncthreads();
        if (t < BK) sc[t] = cnt[t];
        __syncthreads();
        for (int o = 1; o < BK; o <<= 1) {
            int v = (t < BK && t >= o) ? sc[t - o] : 0;
            __syncthreads();
            if (t < BK) sc[t] += v;
            __syncthreads();
        }
        if (t < BK) {
            int c = cnt[t];
            off[t] = sc[t] - c;                      // exclusive prefix
            if (n0 + t < N) {
                begend[n0 + t] = make_int2(beg + off[t], beg + sc[t]);
                dinv[n0 + t] = rsqrtf((float)c + 1.0f);
            }
            cnt[t] = 0;                              // becomes fill counter
        }
        __syncthreads();
        for (int i = t; i < ecnt; i += 256) {
            int e = ebuf[beg + i];
            int dl = e >> 20;
            int p = beg + off[dl] + atomicAdd(&cnt[dl], 1);
            col[p] = e & 0xFFFFF;
        }
        return;
    }

    // ---- MFMA GEMM1 tile ----
    const int row0 = ((int)blockIdx.x - NBK) * 64;
    {
        int r = t >> 2, cc = (t & 3) * 32;
        int grow = row0 + r;
        unsigned int* dst = (unsigned int*)&lds[r * 136 + cc];
        if (grow < N) {
            const float4* src = (const float4*)(x + (size_t)grow * 128 + cc);
            #pragma unroll
            for (int i = 0; i < 8; ++i) {
                float4 v = src[i];
                dst[2 * i]     = pack2(v.x, v.y);
                dst[2 * i + 1] = pack2(v.z, v.w);
            }
        } else {
            #pragma unroll
            for (int i = 0; i < 16; ++i) dst[i] = 0;
        }
    }
    __syncthreads();
    const int w = t >> 6, lane = t & 63;
    const int quad = lane >> 4, m = lane & 15;
    short8 a[4];
    #pragma unroll
    for (int ks = 0; ks < 4; ++ks)
        a[ks] = *(const short8*)&lds[(w * 16 + m) * 136 + ks * 32 + quad * 8];
    float4v acc[8];
    #pragma unroll
    for (int nt = 0; nt < 8; ++nt) acc[nt] = (float4v){0.f, 0.f, 0.f, 0.f};
    const short8* wf = (const short8*)w1f;
    #pragma unroll
    for (int nt = 0; nt < 8; ++nt)
        #pragma unroll
        for (int ks = 0; ks < 4; ++ks)
            acc[nt] = __builtin_amdgcn_mfma_f32_16x16x32_bf16(a[ks], wf[(nt * 4 + ks) * 64 + lane],
                                                              acc[nt], 0, 0, 0);
    float drr[4];
    #pragma unroll
    for (int r = 0; r < 4; ++r) {
        int grow = row0 + w * 16 + quad * 4 + r;
        drr[r] = (grow < N) ? rsqrtf((float)deg[grow] + 1.0f) : 0.0f;
    }
    #pragma unroll
    for (int nt = 0; nt < 8; ++nt)
        #pragma unroll
        for (int r = 0; r < 4; ++r) {
            int grow = row0 + w * 16 + quad * 4 + r;   // C/D: col=lane&15, row=quad*4+reg
            if (grow < N) h[(size_t)grow * 128 + nt * 16 + m] = f2b(acc[nt][r] * drr[r]);
        }
}

// ---------------- fused agg layer 1 + bias + ReLU + GEMM2 (h2 = h1 @ W2, pre-scaled) ----
// feat rows pre-scaled by dinv[src]: inner loop is pure gather-sum (col -> feat only).
// After per-node bias/ReLU, the block's 16 h1 rows go through a 16x128 @ 128x64 MFMA
// epilogue; h2 rows are written pre-scaled by dinv[row] for the layer-2 aggregation.
__global__ __launch_bounds__(256) void k_aggmg2(const uint4* __restrict__ feat,
                                                const int2* __restrict__ begend,
                                                const int* __restrict__ col,
                                                const float* __restrict__ dinv,
                                                const float* __restrict__ b1,
                                                const unsigned short* __restrict__ w2f,
                                                unsigned short* __restrict__ h2, int N) {
    __shared__ unsigned short lds[16 * 136];           // 16 h1 rows, stride 136 bf16
    __shared__ float dvs[16];                          // dinv of the 16 nodes
    const int grp = threadIdx.x >> 4;                  // 16 groups per block
    const int l16 = threadIdx.x & 15;
    const int node = blockIdx.x * 16 + grp;
    float a0 = 0.f, a1 = 0.f, a2 = 0.f, a3 = 0.f, a4 = 0.f, a5 = 0.f, a6 = 0.f, a7 = 0.f;
    if (node < N) {
        const float dd = dinv[node];
        if (l16 == 0) dvs[grp] = dd;
        const int2 be = begend[node];
        const int beg = be.x, end = be.y;
        {
            uint4 sv = feat[(size_t)node * 16 + l16];  // self-loop (row already * dinv[node])
            float2 q;
            q = bf2_to_f2(sv.x); a0 = q.x; a1 = q.y;
            q = bf2_to_f2(sv.y); a2 = q.x; a3 = q.y;
            q = bf2_to_f2(sv.z); a4 = q.x; a5 = q.y;
            q = bf2_to_f2(sv.w); a6 = q.x; a7 = q.y;
        }
        int e = beg;
        for (; e + 4 <= end; e += 4) {
            int s0 = col[e], s1 = col[e + 1], s2 = col[e + 2], s3 = col[e + 3];
            uint4 u0 = feat[(size_t)s0 * 16 + l16];
            uint4 u1 = feat[(size_t)s1 * 16 + l16];
            uint4 u2 = feat[(size_t)s2 * 16 + l16];
            uint4 u3 = feat[(size_t)s3 * 16 + l16];
            float2 q;
            q = bf2_to_f2(u0.x); a0 += q.x; a1 += q.y;
            q = bf2_to_f2(u0.y); a2 += q.x; a3 += q.y;
            q = bf2_to_f2(u0.z); a4 += q.x; a5 += q.y;
            q = bf2_to_f2(u0.w); a6 += q.x; a7 += q.y;
            q = bf2_to_f2(u1.x); a0 += q.x; a1 += q.y;
            q = bf2_to_f2(u1.y); a2 += q.x; a3 += q.y;
            q = bf2_to_f2(u1.z); a4 += q.x; a5 += q.y;
            q = bf2_to_f2(u1.w); a6 += q.x; a7 += q.y;
            q = bf2_to_f2(u2.x); a0 += q.x; a1 += q.y;
            q = bf2_to_f2(u2.y); a2 += q.x; a3 += q.y;
            q = bf2_to_f2(u2.z); a4 += q.x; a5 += q.y;
            q = bf2_to_f2(u2.w); a6 += q.x; a7 += q.y;
            q = bf2_to_f2(u3.x); a0 += q.x; a1 += q.y;
            q = bf2_to_f2(u3.y); a2 += q.x; a3 += q.y;
            q = bf2_to_f2(u3.z); a4 += q.x; a5 += q.y;
            q = bf2_to_f2(u3.w); a6 += q.x; a7 += q.y;
        }
        for (; e < end; ++e) {
            int s = col[e];
            uint4 u = feat[(size_t)s * 16 + l16];
            float2 q;
            q = bf2_to_f2(u.x); a0 += q.x; a1 += q.y;
            q = bf2_to_f2(u.y); a2 += q.x; a3 += q.y;
            q = bf2_to_f2(u.z); a4 += q.x; a5 += q.y;
            q = bf2_to_f2(u.w); a6 += q.x; a7 += q.y;
        }
        float4 ba = ((const float4*)b1)[2 * l16];
        float4 bb = ((const float4*)b1)[2 * l16 + 1];
        a0 = fmaxf(a0 * dd + ba.x, 0.0f);
        a1 = fmaxf(a1 * dd + ba.y, 0.0f);
        a2 = fmaxf(a2 * dd + ba.z, 0.0f);
        a3 = fmaxf(a3 * dd + ba.w, 0.0f);
        a4 = fmaxf(a4 * dd + bb.x, 0.0f);
        a5 = fmaxf(a5 * dd + bb.y, 0.0f);
        a6 = fmaxf(a6 * dd + bb.z, 0.0f);
        a7 = fmaxf(a7 * dd + bb.w, 0.0f);
    } else if (l16 == 0) dvs[grp] = 0.f;
    {   // stage h1 row to LDS (bf16)
        uint4 o;
        o.x = pack2(a0, a1);
        o.y = pack2(a2, a3);
        o.z = pack2(a4, a5);
        o.w = pack2(a6, a7);
        *(uint4*)&lds[grp * 136 + l16 * 8] = o;
    }
    __syncthreads();
    // ---- MFMA GEMM2 epilogue: 16x128 @ 128x64; wave w computes output col-tile w ----
    const int w = threadIdx.x >> 6, lane = threadIdx.x & 63;
    const int quad = lane >> 4, m = lane & 15;
    short8 a[4];
    #pragma unroll
    for (int ks = 0; ks < 4; ++ks)
        a[ks] = *(const short8*)&lds[m * 136 + ks * 32 + quad * 8];
    float4v acc = (float4v){0.f, 0.f, 0.f, 0.f};
    const short8* wf = (const short8*)w2f;
    #pragma unroll
    for (int ks = 0; ks < 4; ++ks)
        acc = __builtin_amdgcn_mfma_f32_16x16x32_bf16(a[ks], wf[(w * 4 + ks) * 64 + lane],
                                                      acc, 0, 0, 0);
    const int node0 = blockIdx.x * 16;
    #pragma unroll
    for (int r = 0; r < 4; ++r) {
        int gn = node0 + quad * 4 + r;                // C/D: col=lane&15, row=quad*4+reg
        if (gn < N) h2[(size_t)gn * 64 + w * 16 + m] = f2b(acc[r] * dvs[quad * 4 + r]);
    }
}

// ---------------- agg layer 2: one node per 16 lanes, +b2, out fp32 ----------------
// h2 rows pre-scaled by dinv[src]: pure gather-sum.
__global__ __launch_bounds__(256) void k_agg64(const uint2* __restrict__ feat,
                                               const int2* __restrict__ begend,
                                               const int* __restrict__ col,
                                               const float* __restrict__ dinv,
                                               const float* __restrict__ bias,
                                               float* __restrict__ out, int N) {
    const int grp = threadIdx.x >> 4;
    const int l16 = threadIdx.x & 15;
    const int node = blockIdx.x * 16 + grp;
    if (node >= N) return;
    const float dd = dinv[node];
    const int2 be = begend[node];
    const int beg = be.x, end = be.y;
    float a0, a1, a2, a3;
    {
        uint2 sv = feat[(size_t)node * 16 + l16];      // self-loop (pre-scaled)
        float2 q;
        q = bf2_to_f2(sv.x); a0 = q.x; a1 = q.y;
        q = bf2_to_f2(sv.y); a2 = q.x; a3 = q.y;
    }
    int e = beg;
    for (; e + 4 <= end; e += 4) {
        int s0 = col[e], s1 = col[e + 1], s2 = col[e + 2], s3 = col[e + 3];
        uint2 u0 = feat[(size_t)s0 * 16 + l16];
        uint2 u1 = feat[(size_t)s1 * 16 + l16];
        uint2 u2 = feat[(size_t)s2 * 16 + l16];
        uint2 u3 = feat[(size_t)s3 * 16 + l16];
        float2 q;
        q = bf2_to_f2(u0.x); a0 += q.x; a1 += q.y;
        q = bf2_to_f2(u0.y); a2 += q.x; a3 += q.y;
        q = bf2_to_f2(u1.x); a0 += q.x; a1 += q.y;
        q = bf2_to_f2(u1.y); a2 += q.x; a3 += q.y;
        q = bf2_to_f2(u2.x); a0 += q.x; a1 += q.y;
        q = bf2_to_f2(u2.y); a2 += q.x; a3 += q.y;
        q = bf2_to_f2(u3.x); a0 += q.x; a1 += q.y;
        q = bf2_to_f2(u3.y); a2 += q.x; a3 += q.y;
    }
    for (; e < end; ++e) {
        int s = col[e];
        uint2 u = feat[(size_t)s * 16 + l16];
        float2 q;
        q = bf2_to_f2(u.x); a0 += q.x; a1 += q.y;
        q = bf2_to_f2(u.y); a2 += q.x; a3 += q.y;
    }
    float4 b = ((const float4*)bias)[l16];
    float4 o;
    o.x = a0 * dd + b.x;
    o.y = a1 * dd + b.y;
    o.z = a2 * dd + b.z;
    o.w = a3 * dd + b.w;
    ((float4*)out)[(size_t)node * 16 + l16] = o;
}

extern "C" void kernel_launch(void* const* d_in, const int* in_sizes, int n_in,
                              void* d_out, int out_size, void* d_ws, size_t ws_size,
                              hipStream_t stream) {
    const float* x  = (const float*)d_in[0];
    const int*   ei = (const int*)d_in[1];
    const float* W1 = (const float*)d_in[2];
    const float* b1 = (const float*)d_in[3];
    const float* W2 = (const float*)d_in[4];
    const float* b2 = (const float*)d_in[5];

    const int N = in_sizes[0] / IN_C;               // 50000
    const int E = in_sizes[1] / 2;                  // 800000
    const int NBK  = (N + BK - 1) / BK;             // 391 buckets
    const int NCHK = (E + 2047) / 2048;             // 391 edge chunks
    const int NT1  = (N + 63) / 64;                 // 782 GEMM tiles

    char* ws = (char*)d_ws;
    int*            flag    = (int*)(ws + 0);
    int*            bfill   = (int*)(ws + 64);
    int2*           begend  = (int2*)(ws + 4096);
    float*          dinv    = (float*)(ws + 404480);
    unsigned short* w1f     = (unsigned short*)(ws + 604672);
    unsigned short* w2f     = (unsigned short*)(ws + 637440);
    int*            ebuf    = (int*)(ws + 655360);               // NBK<<CAPLG packed ints
    int*            col     = (int*)(ws + 7061504);
    unsigned short* h       = (unsigned short*)(ws + 13467904);  // bf16 [N,128], pre-scaled
    unsigned short* h2      = (unsigned short*)(ws + 26267904);  // bf16 [N,64], pre-scaled
    int*            deg     = (int*)(ws + 32668160);             // int[N]

    // ---- setup (weights + dtype probe + bfill/deg zero) ----
    k_setup<<<96, 256, 0, stream>>>(W1, W2, ei, w1f, w2f, flag, bfill, deg, NBK, N);

    // ---- single-pass bucket partition (fixed-capacity regions) + deg histogram ----
    k_bpart<<<NCHK, 256, 0, stream>>>(ei, flag, bfill, deg, ebuf, E, NBK);

    // ---- fused: bucket-local CSR finalize + GEMM1 (h pre-scaled by dinv) ----
    k_blmg1<<<NBK + NT1, 256, 0, stream>>>(ebuf, bfill, begend, dinv, col,
                                           x, w1f, deg, h, N, NBK);

    // ---- fused layer-1 aggregation (+b1, ReLU) + GEMM2 MFMA epilogue ----
    k_aggmg2<<<(N + 15) / 16, 256, 0, stream>>>((const uint4*)h, begend, col, dinv, b1,
                                                w2f, h2, N);

    // ---- layer 2 aggregation (+b2, fp32 out) ----
    k_agg64<<<(N + 15) / 16, 256, 0, stream>>>((const uint2*)h2, begend, col, dinv, b2,
                                               (float*)d_out, N);
}

// Round 2
// 167.989 us; speedup vs baseline: 1.1606x; 1.1606x over previous
//
#include <hip/hip_runtime.h>
#include <hip/hip_bf16.h>

#define IN_C  128
#define HID_C 128
#define OUT_CC 64
#define BK    128           // nodes per bucket (dst >> 7)
#define CAPLG 12            // bucket capacity 4096 edges (mean 2046, >40 sigma)

using short8  = __attribute__((ext_vector_type(8))) short;
using float4v = __attribute__((ext_vector_type(4))) float;

// fp32 -> bf16 (round-to-nearest-even, finite inputs)
__device__ __forceinline__ unsigned short f2b(float f) {
    unsigned int u = __float_as_uint(f);
    return (unsigned short)((u + 0x7fffu + ((u >> 16) & 1u)) >> 16);
}
__device__ __forceinline__ unsigned int pack2(float a, float b) {
    return (unsigned int)f2b(a) | ((unsigned int)f2b(b) << 16);
}
__device__ __forceinline__ float2 bf2_to_f2(unsigned int v) {
    float2 r;
    r.x = __uint_as_float(v << 16);
    r.y = __uint_as_float(v & 0xffff0000u);
    return r;
}

// ---- ws layout (bytes) ----
// flag      int            @ 0
// bfill     int[391]       @ 64
// begend    int2[N]        @ 4096       (ends 404,096)
// dinv      float[N]       @ 404480     (ends 604,480)
// w1frag    bf16[16384]    @ 604672
// w2frag    bf16[8192]     @ 637440
// ebuf      int[391*4096]  @ 655360     (packed src|dlocal<<20; ends 7,061,504)
// col       int[391*4096]  @ 7061504    (ends 13,467,648)
// h (bf16)  [N*128]        @ 13467904   (pre-scaled by dinv[row]; ends 26,267,904)
// h2(bf16)  [N*64]         @ 26267904   (pre-scaled by dinv[row]; ends 32,667,904)

// ---------------- setup: weight prep + edge dtype probe + bfill zero ----------------
__global__ __launch_bounds__(256) void k_setup(const float* __restrict__ W1,
                                               const float* __restrict__ W2,
                                               const int* __restrict__ ei,
                                               unsigned short* __restrict__ w1f,
                                               unsigned short* __restrict__ w2f,
                                               int* __restrict__ flag,
                                               int* __restrict__ bfill, int NBK) {
    int e = blockIdx.x * 256 + threadIdx.x;
    if (e < 16384) {                                  // W1: frag ((nt*4+ks)*64+lane)*8+j
        int j = e & 7, lane = (e >> 3) & 63, ks = (e >> 9) & 3, nt = e >> 11;
        int k = ks * 32 + ((lane >> 4) << 3) + j;
        int n = nt * 16 + (lane & 15);
        w1f[e] = f2b(W1[k * 128 + n]);
    } else if (e < 16384 + 8192) {
        int e2 = e - 16384;
        int j = e2 & 7, lane = (e2 >> 3) & 63, ks = (e2 >> 9) & 3, nt = e2 >> 11;
        int k = ks * 32 + ((lane >> 4) << 3) + j;
        int n = nt * 16 + (lane & 15);
        w2f[e2] = f2b(W2[k * 64 + n]);
    }
    if (blockIdx.x == 0) {
        for (int i = threadIdx.x; i < NBK; i += 256) bfill[i] = 0;
        if (threadIdx.x == 0) {
            int odd_zero = 1, any_even = 0;
            for (int i = 0; i < 64; ++i) {
                if (ei[2 * i + 1] != 0) odd_zero = 0;
                if (ei[2 * i] != 0) any_even = 1;
            }
            *flag = (odd_zero && any_even) ? 2 : 1;
        }
    }
}

// ---------------- partition edges into fixed-capacity bucket regions ----------------
// ebuf[b<<CAPLG + rank] = src | (dst & 127) << 20
__global__ __launch_bounds__(256) void k_bpart(const int* __restrict__ ei,
                                               const int* __restrict__ flag,
                                               int* __restrict__ bfill,
                                               int* __restrict__ ebuf, int E, int NBK) {
    __shared__ int lh[512];
    __shared__ int lbase[512];
    const int t = threadIdx.x;
    for (int i = t; i < NBK; i += 256) lh[i] = 0;
    __syncthreads();
    const int st = *flag;
    const int base = blockIdx.x * 2048;
    int s[8], d[8];
    #pragma unroll
    for (int j = 0; j < 8; ++j) {
        int i = base + j * 256 + t;
        if (i < E) {
            s[j] = ei[(size_t)st * i];
            d[j] = ei[(size_t)st * ((size_t)E + i)];
            atomicAdd(&lh[d[j] >> 7], 1);
        } else d[j] = -1;
    }
    __syncthreads();
    for (int i = t; i < NBK; i += 256) {
        int c = lh[i];
        lbase[i] = c ? atomicAdd(&bfill[i], c) : 0;
        lh[i] = 0;                                   // becomes local rank counter
    }
    __syncthreads();
    #pragma unroll
    for (int j = 0; j < 8; ++j) {
        if (d[j] >= 0) {
            int b = d[j] >> 7;
            int r = lbase[b] + atomicAdd(&lh[b], 1);
            if (r < (1 << CAPLG))                    // statistical safety clamp
                ebuf[(b << CAPLG) + r] = s[j] | ((d[j] & (BK - 1)) << 20);
        }
    }
}

// ---------------- fused: per-bucket local CSR (blocks < NBK) | MFMA GEMM1 (rest) ----
// GEMM1 tiles write h pre-scaled by dinv[row]. Row degrees are computed LOCALLY per
// tile by scanning the owning bucket's ebuf region into a 64-entry LDS histogram
// (no global deg array, no ordering dependence on the CSR blocks).
__global__ __launch_bounds__(256) void k_blmg1(const int* __restrict__ ebuf,
                                               const int* __restrict__ bfill,
                                               int2* __restrict__ begend,
                                               float* __restrict__ dinv,
                                               int* __restrict__ col,
                                               const float* __restrict__ x,
                                               const unsigned short* __restrict__ w1f,
                                               unsigned short* __restrict__ h,
                                               int N, int NBK) {
    __shared__ unsigned short lds[64 * 136];          // 17.4 KB, shared by both paths
    __shared__ int cnt64[64];                         // GEMM path: local row degrees
    const int t = threadIdx.x;

    if ((int)blockIdx.x < NBK) {
        // ---- per-bucket CSR build ----
        int* cnt = (int*)lds;
        int* sc  = cnt + BK;
        int* off = sc + BK;
        const int n0 = blockIdx.x * BK;
        const int beg = (int)blockIdx.x << CAPLG;
        const int ecnt = min(bfill[blockIdx.x], 1 << CAPLG);
        if (t < BK) cnt[t] = 0;
        __syncthreads();
        for (int i = t; i < ecnt; i += 256)
            atomicAdd(&cnt[ebuf[beg + i] >> 20], 1);
        __syncthreads();
        if (t < BK) sc[t] = cnt[t];
        __syncthreads();
        for (int o = 1; o < BK; o <<= 1) {
            int v = (t < BK && t >= o) ? sc[t - o] : 0;
            __syncthreads();
            if (t < BK) sc[t] += v;
            __syncthreads();
        }
        if (t < BK) {
            int c = cnt[t];
            off[t] = sc[t] - c;                      // exclusive prefix
            if (n0 + t < N) {
                begend[n0 + t] = make_int2(beg + off[t], beg + sc[t]);
                dinv[n0 + t] = rsqrtf((float)c + 1.0f);
            }
            cnt[t] = 0;                              // becomes fill counter
        }
        __syncthreads();
        for (int i = t; i < ecnt; i += 256) {
            int e = ebuf[beg + i];
            int dl = e >> 20;
            int p = beg + off[dl] + atomicAdd(&cnt[dl], 1);
            col[p] = e & 0xFFFFF;
        }
        return;
    }

    // ---- MFMA GEMM1 tile ----
    const int tile = (int)blockIdx.x - NBK;
    const int row0 = tile * 64;
    const int bkt  = row0 >> 7;                       // owning bucket
    const int half = (row0 >> 6) & 1;                 // which 64-row half of the bucket
    if (t < 64) cnt64[t] = 0;
    __syncthreads();
    {   // local degree histogram: scan bucket's packed edges, filter to our half
        const int ebeg = bkt << CAPLG;
        const int ecnt = min(bfill[bkt], 1 << CAPLG);
        for (int i = t; i < ecnt; i += 256) {
            int dl = ebuf[ebeg + i] >> 20;
            if ((dl >> 6) == half) atomicAdd(&cnt64[dl & 63], 1);
        }
    }
    {   // stage x tile to LDS as bf16
        int r = t >> 2, cc = (t & 3) * 32;
        int grow = row0 + r;
        unsigned int* dst = (unsigned int*)&lds[r * 136 + cc];
        if (grow < N) {
            const float4* src = (const float4*)(x + (size_t)grow * 128 + cc);
            #pragma unroll
            for (int i = 0; i < 8; ++i) {
                float4 v = src[i];
                dst[2 * i]     = pack2(v.x, v.y);
                dst[2 * i + 1] = pack2(v.z, v.w);
            }
        } else {
            #pragma unroll
            for (int i = 0; i < 16; ++i) dst[i] = 0;
        }
    }
    __syncthreads();
    const int w = t >> 6, lane = t & 63;
    const int quad = lane >> 4, m = lane & 15;
    short8 a[4];
    #pragma unroll
    for (int ks = 0; ks < 4; ++ks)
        a[ks] = *(const short8*)&lds[(w * 16 + m) * 136 + ks * 32 + quad * 8];
    float4v acc[8];
    #pragma unroll
    for (int nt = 0; nt < 8; ++nt) acc[nt] = (float4v){0.f, 0.f, 0.f, 0.f};
    const short8* wf = (const short8*)w1f;
    #pragma unroll
    for (int nt = 0; nt < 8; ++nt)
        #pragma unroll
        for (int ks = 0; ks < 4; ++ks)
            acc[nt] = __builtin_amdgcn_mfma_f32_16x16x32_bf16(a[ks], wf[(nt * 4 + ks) * 64 + lane],
                                                              acc[nt], 0, 0, 0);
    float drr[4];
    #pragma unroll
    for (int r = 0; r < 4; ++r) {
        int lr = w * 16 + quad * 4 + r;               // local row in tile
        drr[r] = rsqrtf((float)cnt64[lr] + 1.0f);
    }
    #pragma unroll
    for (int nt = 0; nt < 8; ++nt)
        #pragma unroll
        for (int r = 0; r < 4; ++r) {
            int grow = row0 + w * 16 + quad * 4 + r;   // C/D: col=lane&15, row=quad*4+reg
            if (grow < N) h[(size_t)grow * 128 + nt * 16 + m] = f2b(acc[nt][r] * drr[r]);
        }
}

// ---------------- fused agg layer 1 + bias + ReLU + GEMM2 (h2 = h1 @ W2, pre-scaled) ----
// feat rows pre-scaled by dinv[src]: inner loop is pure gather-sum (col -> feat only).
// After per-node bias/ReLU, the block's 16 h1 rows go through a 16x128 @ 128x64 MFMA
// epilogue; h2 rows are written pre-scaled by dinv[row] for the layer-2 aggregation.
__global__ __launch_bounds__(256) void k_aggmg2(const uint4* __restrict__ feat,
                                                const int2* __restrict__ begend,
                                                const int* __restrict__ col,
                                                const float* __restrict__ dinv,
                                                const float* __restrict__ b1,
                                                const unsigned short* __restrict__ w2f,
                                                unsigned short* __restrict__ h2, int N) {
    __shared__ unsigned short lds[16 * 136];           // 16 h1 rows, stride 136 bf16
    __shared__ float dvs[16];                          // dinv of the 16 nodes
    const int grp = threadIdx.x >> 4;                  // 16 groups per block
    const int l16 = threadIdx.x & 15;
    const int node = blockIdx.x * 16 + grp;
    float a0 = 0.f, a1 = 0.f, a2 = 0.f, a3 = 0.f, a4 = 0.f, a5 = 0.f, a6 = 0.f, a7 = 0.f;
    if (node < N) {
        const float dd = dinv[node];
        if (l16 == 0) dvs[grp] = dd;
        const int2 be = begend[node];
        const int beg = be.x, end = be.y;
        {
            uint4 sv = feat[(size_t)node * 16 + l16];  // self-loop (row already * dinv[node])
            float2 q;
            q = bf2_to_f2(sv.x); a0 = q.x; a1 = q.y;
            q = bf2_to_f2(sv.y); a2 = q.x; a3 = q.y;
            q = bf2_to_f2(sv.z); a4 = q.x; a5 = q.y;
            q = bf2_to_f2(sv.w); a6 = q.x; a7 = q.y;
        }
        int e = beg;
        for (; e + 4 <= end; e += 4) {
            int s0 = col[e], s1 = col[e + 1], s2 = col[e + 2], s3 = col[e + 3];
            uint4 u0 = feat[(size_t)s0 * 16 + l16];
            uint4 u1 = feat[(size_t)s1 * 16 + l16];
            uint4 u2 = feat[(size_t)s2 * 16 + l16];
            uint4 u3 = feat[(size_t)s3 * 16 + l16];
            float2 q;
            q = bf2_to_f2(u0.x); a0 += q.x; a1 += q.y;
            q = bf2_to_f2(u0.y); a2 += q.x; a3 += q.y;
            q = bf2_to_f2(u0.z); a4 += q.x; a5 += q.y;
            q = bf2_to_f2(u0.w); a6 += q.x; a7 += q.y;
            q = bf2_to_f2(u1.x); a0 += q.x; a1 += q.y;
            q = bf2_to_f2(u1.y); a2 += q.x; a3 += q.y;
            q = bf2_to_f2(u1.z); a4 += q.x; a5 += q.y;
            q = bf2_to_f2(u1.w); a6 += q.x; a7 += q.y;
            q = bf2_to_f2(u2.x); a0 += q.x; a1 += q.y;
            q = bf2_to_f2(u2.y); a2 += q.x; a3 += q.y;
            q = bf2_to_f2(u2.z); a4 += q.x; a5 += q.y;
            q = bf2_to_f2(u2.w); a6 += q.x; a7 += q.y;
            q = bf2_to_f2(u3.x); a0 += q.x; a1 += q.y;
            q = bf2_to_f2(u3.y); a2 += q.x; a3 += q.y;
            q = bf2_to_f2(u3.z); a4 += q.x; a5 += q.y;
            q = bf2_to_f2(u3.w); a6 += q.x; a7 += q.y;
        }
        for (; e < end; ++e) {
            int s = col[e];
            uint4 u = feat[(size_t)s * 16 + l16];
            float2 q;
            q = bf2_to_f2(u.x); a0 += q.x; a1 += q.y;
            q = bf2_to_f2(u.y); a2 += q.x; a3 += q.y;
            q = bf2_to_f2(u.z); a4 += q.x; a5 += q.y;
            q = bf2_to_f2(u.w); a6 += q.x; a7 += q.y;
        }
        float4 ba = ((const float4*)b1)[2 * l16];
        float4 bb = ((const float4*)b1)[2 * l16 + 1];
        a0 = fmaxf(a0 * dd + ba.x, 0.0f);
        a1 = fmaxf(a1 * dd + ba.y, 0.0f);
        a2 = fmaxf(a2 * dd + ba.z, 0.0f);
        a3 = fmaxf(a3 * dd + ba.w, 0.0f);
        a4 = fmaxf(a4 * dd + bb.x, 0.0f);
        a5 = fmaxf(a5 * dd + bb.y, 0.0f);
        a6 = fmaxf(a6 * dd + bb.z, 0.0f);
        a7 = fmaxf(a7 * dd + bb.w, 0.0f);
    } else if (l16 == 0) dvs[grp] = 0.f;
    {   // stage h1 row to LDS (bf16)
        uint4 o;
        o.x = pack2(a0, a1);
        o.y = pack2(a2, a3);
        o.z = pack2(a4, a5);
        o.w = pack2(a6, a7);
        *(uint4*)&lds[grp * 136 + l16 * 8] = o;
    }
    __syncthreads();
    // ---- MFMA GEMM2 epilogue: 16x128 @ 128x64; wave w computes output col-tile w ----
    const int w = threadIdx.x >> 6, lane = threadIdx.x & 63;
    const int quad = lane >> 4, m = lane & 15;
    short8 a[4];
    #pragma unroll
    for (int ks = 0; ks < 4; ++ks)
        a[ks] = *(const short8*)&lds[m * 136 + ks * 32 + quad * 8];
    float4v acc = (float4v){0.f, 0.f, 0.f, 0.f};
    const short8* wf = (const short8*)w2f;
    #pragma unroll
    for (int ks = 0; ks < 4; ++ks)
        acc = __builtin_amdgcn_mfma_f32_16x16x32_bf16(a[ks], wf[(w * 4 + ks) * 64 + lane],
                                                      acc, 0, 0, 0);
    const int node0 = blockIdx.x * 16;
    #pragma unroll
    for (int r = 0; r < 4; ++r) {
        int gn = node0 + quad * 4 + r;                // C/D: col=lane&15, row=quad*4+reg
        if (gn < N) h2[(size_t)gn * 64 + w * 16 + m] = f2b(acc[r] * dvs[quad * 4 + r]);
    }
}

// ---------------- agg layer 2: one node per 16 lanes, +b2, out fp32 ----------------
// h2 rows pre-scaled by dinv[src]: pure gather-sum.
__global__ __launch_bounds__(256) void k_agg64(const uint2* __restrict__ feat,
                                               const int2* __restrict__ begend,
                                               const int* __restrict__ col,
                                               const float* __restrict__ dinv,
                                               const float* __restrict__ bias,
                                               float* __restrict__ out, int N) {
    const int grp = threadIdx.x >> 4;
    const int l16 = threadIdx.x & 15;
    const int node = blockIdx.x * 16 + grp;
    if (node >= N) return;
    const float dd = dinv[node];
    const int2 be = begend[node];
    const int beg = be.x, end = be.y;
    float a0, a1, a2, a3;
    {
        uint2 sv = feat[(size_t)node * 16 + l16];      // self-loop (pre-scaled)
        float2 q;
        q = bf2_to_f2(sv.x); a0 = q.x; a1 = q.y;
        q = bf2_to_f2(sv.y); a2 = q.x; a3 = q.y;
    }
    int e = beg;
    for (; e + 4 <= end; e += 4) {
        int s0 = col[e], s1 = col[e + 1], s2 = col[e + 2], s3 = col[e + 3];
        uint2 u0 = feat[(size_t)s0 * 16 + l16];
        uint2 u1 = feat[(size_t)s1 * 16 + l16];
        uint2 u2 = feat[(size_t)s2 * 16 + l16];
        uint2 u3 = feat[(size_t)s3 * 16 + l16];
        float2 q;
        q = bf2_to_f2(u0.x); a0 += q.x; a1 += q.y;
        q = bf2_to_f2(u0.y); a2 += q.x; a3 += q.y;
        q = bf2_to_f2(u1.x); a0 += q.x; a1 += q.y;
        q = bf2_to_f2(u1.y); a2 += q.x; a3 += q.y;
        q = bf2_to_f2(u2.x); a0 += q.x; a1 += q.y;
        q = bf2_to_f2(u2.y); a2 += q.x; a3 += q.y;
        q = bf2_to_f2(u3.x); a0 += q.x; a1 += q.y;
        q = bf2_to_f2(u3.y); a2 += q.x; a3 += q.y;
    }
    for (; e < end; ++e) {
        int s = col[e];
        uint2 u = feat[(size_t)s * 16 + l16];
        float2 q;
        q = bf2_to_f2(u.x); a0 += q.x; a1 += q.y;
        q = bf2_to_f2(u.y); a2 += q.x; a3 += q.y;
    }
    float4 b = ((const float4*)bias)[l16];
    float4 o;
    o.x = a0 * dd + b.x;
    o.y = a1 * dd + b.y;
    o.z = a2 * dd + b.z;
    o.w = a3 * dd + b.w;
    ((float4*)out)[(size_t)node * 16 + l16] = o;
}

extern "C" void kernel_launch(void* const* d_in, const int* in_sizes, int n_in,
                              void* d_out, int out_size, void* d_ws, size_t ws_size,
                              hipStream_t stream) {
    const float* x  = (const float*)d_in[0];
    const int*   ei = (const int*)d_in[1];
    const float* W1 = (const float*)d_in[2];
    const float* b1 = (const float*)d_in[3];
    const float* W2 = (const float*)d_in[4];
    const float* b2 = (const float*)d_in[5];

    const int N = in_sizes[0] / IN_C;               // 50000
    const int E = in_sizes[1] / 2;                  // 800000
    const int NBK  = (N + BK - 1) / BK;             // 391 buckets
    const int NCHK = (E + 2047) / 2048;             // 391 edge chunks
    const int NT1  = (N + 63) / 64;                 // 782 GEMM tiles

    char* ws = (char*)d_ws;
    int*            flag    = (int*)(ws + 0);
    int*            bfill   = (int*)(ws + 64);
    int2*           begend  = (int2*)(ws + 4096);
    float*          dinv    = (float*)(ws + 404480);
    unsigned short* w1f     = (unsigned short*)(ws + 604672);
    unsigned short* w2f     = (unsigned short*)(ws + 637440);
    int*            ebuf    = (int*)(ws + 655360);               // NBK<<CAPLG packed ints
    int*            col     = (int*)(ws + 7061504);
    unsigned short* h       = (unsigned short*)(ws + 13467904);  // bf16 [N,128], pre-scaled
    unsigned short* h2      = (unsigned short*)(ws + 26267904);  // bf16 [N,64], pre-scaled

    // ---- setup (weights + dtype probe + bfill zero) ----
    k_setup<<<96, 256, 0, stream>>>(W1, W2, ei, w1f, w2f, flag, bfill, NBK);

    // ---- single-pass bucket partition (fixed-capacity regions) ----
    k_bpart<<<NCHK, 256, 0, stream>>>(ei, flag, bfill, ebuf, E, NBK);

    // ---- fused: bucket-local CSR finalize + GEMM1 (h pre-scaled via local histogram) ----
    k_blmg1<<<NBK + NT1, 256, 0, stream>>>(ebuf, bfill, begend, dinv, col,
                                           x, w1f, h, N, NBK);

    // ---- fused layer-1 aggregation (+b1, ReLU) + GEMM2 MFMA epilogue ----
    k_aggmg2<<<(N + 15) / 16, 256, 0, stream>>>((const uint4*)h, begend, col, dinv, b1,
                                                w2f, h2, N);

    // ---- layer 2 aggregation (+b2, fp32 out) ----
    k_agg64<<<(N + 15) / 16, 256, 0, stream>>>((const uint2*)h2, begend, col, dinv, b2,
                                               (float*)d_out, N);
}

// Round 3
// 160.509 us; speedup vs baseline: 1.2147x; 1.0466x over previous
//
#include <hip/hip_runtime.h>
#include <hip/hip_bf16.h>

#define IN_C  128
#define HID_C 128
#define OUT_CC 64
#define BK    128           // nodes per bucket (dst >> 7)
#define CAPLG 12            // bucket capacity 4096 edges (mean 2046, >40 sigma)

using short8  = __attribute__((ext_vector_type(8))) short;
using float4v = __attribute__((ext_vector_type(4))) float;

// fp32 -> bf16 (round-to-nearest-even, finite inputs)
__device__ __forceinline__ unsigned short f2b(float f) {
    unsigned int u = __float_as_uint(f);
    return (unsigned short)((u + 0x7fffu + ((u >> 16) & 1u)) >> 16);
}
__device__ __forceinline__ unsigned int pack2(float a, float b) {
    return (unsigned int)f2b(a) | ((unsigned int)f2b(b) << 16);
}
__device__ __forceinline__ float2 bf2_to_f2(unsigned int v) {
    float2 r;
    r.x = __uint_as_float(v << 16);
    r.y = __uint_as_float(v & 0xffff0000u);
    return r;
}

// ---- ws layout (bytes) ----
// bfill     int[391]       @ 64         (zeroed via hipMemsetAsync)
// begend    int2[N]        @ 4096       (ends 404,096)
// dinv      float[N]       @ 404480     (ends 604,480)
// w1frag    bf16[16384]    @ 604672
// w2frag    bf16[8192]     @ 637440
// ebuf      int[391*4096]  @ 655360     (packed src|dlocal<<20; ends 7,061,504)
// col       int[391*4096]  @ 7061504    (ends 13,467,648)
// h (bf16)  [N*128]        @ 13467904   (pre-scaled by dinv[row]; ends 26,267,904)
// h2(bf16)  [N*64]         @ 26267904   (pre-scaled by dinv[row]; ends 32,667,904)

// ---------------- fused: edge partition (blocks < NCHK) | weight prep (rest) --------
// Edge blocks: dtype probe via wave-0 ballot, then fixed-capacity bucket partition.
// ebuf[b<<CAPLG + rank] = src | (dst & 127) << 20
__global__ __launch_bounds__(256) void k_bpart(const int* __restrict__ ei,
                                               int* __restrict__ bfill,
                                               int* __restrict__ ebuf, int E, int NBK,
                                               int NCHK,
                                               const float* __restrict__ W1,
                                               const float* __restrict__ W2,
                                               unsigned short* __restrict__ w1f,
                                               unsigned short* __restrict__ w2f) {
    const int t = threadIdx.x;
    if ((int)blockIdx.x >= NCHK) {                   // ---- weight prep blocks ----
        int e = ((int)blockIdx.x - NCHK) * 256 + t;
        if (e < 16384) {                             // W1: frag ((nt*4+ks)*64+lane)*8+j
            int j = e & 7, lane = (e >> 3) & 63, ks = (e >> 9) & 3, nt = e >> 11;
            int k = ks * 32 + ((lane >> 4) << 3) + j;
            int n = nt * 16 + (lane & 15);
            w1f[e] = f2b(W1[k * 128 + n]);
        } else if (e < 16384 + 8192) {
            int e2 = e - 16384;
            int j = e2 & 7, lane = (e2 >> 3) & 63, ks = (e2 >> 9) & 3, nt = e2 >> 11;
            int k = ks * 32 + ((lane >> 4) << 3) + j;
            int n = nt * 16 + (lane & 15);
            w2f[e2] = f2b(W2[k * 64 + n]);
        }
        return;
    }
    __shared__ int lh[512];
    __shared__ int lbase[512];
    __shared__ int s_st;
    for (int i = t; i < NBK; i += 256) lh[i] = 0;
    if (t < 64) {                                    // dtype probe (int64 vs int32)
        int ev = ei[2 * t], od = ei[2 * t + 1];
        unsigned long long onz = __ballot(od != 0);
        unsigned long long enz = __ballot(ev != 0);
        if (t == 0) s_st = (onz == 0ull && enz != 0ull) ? 2 : 1;
    }
    __syncthreads();
    const int st = s_st;
    const int base = blockIdx.x * 2048;
    int s[8], d[8];
    #pragma unroll
    for (int j = 0; j < 8; ++j) {
        int i = base + j * 256 + t;
        if (i < E) {
            s[j] = ei[(size_t)st * i];
            d[j] = ei[(size_t)st * ((size_t)E + i)];
            atomicAdd(&lh[d[j] >> 7], 1);
        } else d[j] = -1;
    }
    __syncthreads();
    for (int i = t; i < NBK; i += 256) {
        int c = lh[i];
        lbase[i] = c ? atomicAdd(&bfill[i], c) : 0;
        lh[i] = 0;                                   // becomes local rank counter
    }
    __syncthreads();
    #pragma unroll
    for (int j = 0; j < 8; ++j) {
        if (d[j] >= 0) {
            int b = d[j] >> 7;
            int r = lbase[b] + atomicAdd(&lh[b], 1);
            if (r < (1 << CAPLG))                    // statistical safety clamp
                ebuf[(b << CAPLG) + r] = s[j] | ((d[j] & (BK - 1)) << 20);
        }
    }
}

// ---------------- fused: per-bucket local CSR (blocks < NBK) | MFMA GEMM1 (rest) ----
// GEMM1 tiles write h pre-scaled by dinv[row]. Row degrees are computed LOCALLY per
// tile by scanning the owning bucket's ebuf region into a 64-entry LDS histogram.
__global__ __launch_bounds__(256) void k_blmg1(const int* __restrict__ ebuf,
                                               const int* __restrict__ bfill,
                                               int2* __restrict__ begend,
                                               float* __restrict__ dinv,
                                               int* __restrict__ col,
                                               const float* __restrict__ x,
                                               const unsigned short* __restrict__ w1f,
                                               unsigned short* __restrict__ h,
                                               int N, int NBK) {
    __shared__ unsigned short lds[64 * 136];          // 17.4 KB, shared by both paths
    __shared__ int cnt64[64];                         // GEMM path: local row degrees
    const int t = threadIdx.x;

    if ((int)blockIdx.x < NBK) {
        // ---- per-bucket CSR build ----
        int* cnt = (int*)lds;
        int* sc  = cnt + BK;
        int* off = sc + BK;
        const int n0 = blockIdx.x * BK;
        const int beg = (int)blockIdx.x << CAPLG;
        const int ecnt = min(bfill[blockIdx.x], 1 << CAPLG);
        if (t < BK) cnt[t] = 0;
        __syncthreads();
        for (int i = t; i < ecnt; i += 256)
            atomicAdd(&cnt[ebuf[beg + i] >> 20], 1);
        __syncthreads();
        if (t < BK) sc[t] = cnt[t];
        __syncthreads();
        for (int o = 1; o < BK; o <<= 1) {
            int v = (t < BK && t >= o) ? sc[t - o] : 0;
            __syncthreads();
            if (t < BK) sc[t] += v;
            __syncthreads();
        }
        if (t < BK) {
            int c = cnt[t];
            off[t] = sc[t] - c;                      // exclusive prefix
            if (n0 + t < N) {
                begend[n0 + t] = make_int2(beg + off[t], beg + sc[t]);
                dinv[n0 + t] = rsqrtf((float)c + 1.0f);
            }
            cnt[t] = 0;                              // becomes fill counter
        }
        __syncthreads();
        for (int i = t; i < ecnt; i += 256) {
            int e = ebuf[beg + i];
            int dl = e >> 20;
            int p = beg + off[dl] + atomicAdd(&cnt[dl], 1);
            col[p] = e & 0xFFFFF;
        }
        return;
    }

    // ---- MFMA GEMM1 tile ----
    const int tile = (int)blockIdx.x - NBK;
    const int row0 = tile * 64;
    const int bkt  = row0 >> 7;                       // owning bucket
    const int half = (row0 >> 6) & 1;                 // which 64-row half of the bucket
    if (t < 64) cnt64[t] = 0;
    __syncthreads();
    {   // local degree histogram: scan bucket's packed edges, filter to our half
        const int ebeg = bkt << CAPLG;
        const int ecnt = min(bfill[bkt], 1 << CAPLG);
        for (int i = t; i < ecnt; i += 256) {
            int dl = ebuf[ebeg + i] >> 20;
            if ((dl >> 6) == half) atomicAdd(&cnt64[dl & 63], 1);
        }
    }
    {   // stage x tile to LDS as bf16
        int r = t >> 2, cc = (t & 3) * 32;
        int grow = row0 + r;
        unsigned int* dst = (unsigned int*)&lds[r * 136 + cc];
        if (grow < N) {
            const float4* src = (const float4*)(x + (size_t)grow * 128 + cc);
            #pragma unroll
            for (int i = 0; i < 8; ++i) {
                float4 v = src[i];
                dst[2 * i]     = pack2(v.x, v.y);
                dst[2 * i + 1] = pack2(v.z, v.w);
            }
        } else {
            #pragma unroll
            for (int i = 0; i < 16; ++i) dst[i] = 0;
        }
    }
    __syncthreads();
    const int w = t >> 6, lane = t & 63;
    const int quad = lane >> 4, m = lane & 15;
    short8 a[4];
    #pragma unroll
    for (int ks = 0; ks < 4; ++ks)
        a[ks] = *(const short8*)&lds[(w * 16 + m) * 136 + ks * 32 + quad * 8];
    float4v acc[8];
    #pragma unroll
    for (int nt = 0; nt < 8; ++nt) acc[nt] = (float4v){0.f, 0.f, 0.f, 0.f};
    const short8* wf = (const short8*)w1f;
    #pragma unroll
    for (int nt = 0; nt < 8; ++nt)
        #pragma unroll
        for (int ks = 0; ks < 4; ++ks)
            acc[nt] = __builtin_amdgcn_mfma_f32_16x16x32_bf16(a[ks], wf[(nt * 4 + ks) * 64 + lane],
                                                              acc[nt], 0, 0, 0);
    float drr[4];
    #pragma unroll
    for (int r = 0; r < 4; ++r) {
        int lr = w * 16 + quad * 4 + r;               // local row in tile
        drr[r] = rsqrtf((float)cnt64[lr] + 1.0f);
    }
    #pragma unroll
    for (int nt = 0; nt < 8; ++nt)
        #pragma unroll
        for (int r = 0; r < 4; ++r) {
            int grow = row0 + w * 16 + quad * 4 + r;   // C/D: col=lane&15, row=quad*4+reg
            if (grow < N) h[(size_t)grow * 128 + nt * 16 + m] = f2b(acc[nt][r] * drr[r]);
        }
}

#define ACC16(u) { float2 q; \
    q = bf2_to_f2(u.x); a0 += q.x; a1 += q.y; \
    q = bf2_to_f2(u.y); a2 += q.x; a3 += q.y; \
    q = bf2_to_f2(u.z); a4 += q.x; a5 += q.y; \
    q = bf2_to_f2(u.w); a6 += q.x; a7 += q.y; }

// ---------------- fused agg layer 1 + bias + ReLU + GEMM2 (h2 = h1 @ W2, pre-scaled) ----
// feat rows pre-scaled by dinv[src]: pure gather-sum with software-pipelined col loads.
// After per-node bias/ReLU, the block's 16 h1 rows go through a 16x128 @ 128x64 MFMA
// epilogue; h2 rows are written pre-scaled by dinv[row] for the layer-2 aggregation.
__global__ __launch_bounds__(256) void k_aggmg2(const uint4* __restrict__ feat,
                                                const int2* __restrict__ begend,
                                                const int* __restrict__ col,
                                                const float* __restrict__ dinv,
                                                const float* __restrict__ b1,
                                                const unsigned short* __restrict__ w2f,
                                                unsigned short* __restrict__ h2, int N) {
    __shared__ unsigned short lds[16 * 136];           // 16 h1 rows, stride 136 bf16
    __shared__ float dvs[16];                          // dinv of the 16 nodes
    const int grp = threadIdx.x >> 4;                  // 16 groups per block
    const int l16 = threadIdx.x & 15;
    const int node = blockIdx.x * 16 + grp;
    float a0 = 0.f, a1 = 0.f, a2 = 0.f, a3 = 0.f, a4 = 0.f, a5 = 0.f, a6 = 0.f, a7 = 0.f;
    if (node < N) {
        const float dd = dinv[node];
        if (l16 == 0) dvs[grp] = dd;
        const int2 be = begend[node];
        int e = be.x; const int end = be.y;
        {
            uint4 sv = feat[(size_t)node * 16 + l16];  // self-loop (row already * dinv[node])
            float2 q;
            q = bf2_to_f2(sv.x); a0 = q.x; a1 = q.y;
            q = bf2_to_f2(sv.y); a2 = q.x; a3 = q.y;
            q = bf2_to_f2(sv.z); a4 = q.x; a5 = q.y;
            q = bf2_to_f2(sv.w); a6 = q.x; a7 = q.y;
        }
        int c0, c1, c2, c3;
        if (e + 4 <= end) { c0 = col[e]; c1 = col[e + 1]; c2 = col[e + 2]; c3 = col[e + 3]; }
        for (; e + 8 <= end; e += 4) {                 // prefetch next quad's col indices
            int n0 = col[e + 4], n1 = col[e + 5], n2 = col[e + 6], n3 = col[e + 7];
            uint4 u0 = feat[(size_t)c0 * 16 + l16];
            uint4 u1 = feat[(size_t)c1 * 16 + l16];
            uint4 u2 = feat[(size_t)c2 * 16 + l16];
            uint4 u3 = feat[(size_t)c3 * 16 + l16];
            ACC16(u0) ACC16(u1) ACC16(u2) ACC16(u3)
            c0 = n0; c1 = n1; c2 = n2; c3 = n3;
        }
        if (e + 4 <= end) {
            uint4 u0 = feat[(size_t)c0 * 16 + l16];
            uint4 u1 = feat[(size_t)c1 * 16 + l16];
            uint4 u2 = feat[(size_t)c2 * 16 + l16];
            uint4 u3 = feat[(size_t)c3 * 16 + l16];
            ACC16(u0) ACC16(u1) ACC16(u2) ACC16(u3)
            e += 4;
        }
        for (; e < end; ++e) {
            uint4 u = feat[(size_t)col[e] * 16 + l16];
            ACC16(u)
        }
        float4 ba = ((const float4*)b1)[2 * l16];
        float4 bb = ((const float4*)b1)[2 * l16 + 1];
        a0 = fmaxf(a0 * dd + ba.x, 0.0f);
        a1 = fmaxf(a1 * dd + ba.y, 0.0f);
        a2 = fmaxf(a2 * dd + ba.z, 0.0f);
        a3 = fmaxf(a3 * dd + ba.w, 0.0f);
        a4 = fmaxf(a4 * dd + bb.x, 0.0f);
        a5 = fmaxf(a5 * dd + bb.y, 0.0f);
        a6 = fmaxf(a6 * dd + bb.z, 0.0f);
        a7 = fmaxf(a7 * dd + bb.w, 0.0f);
    } else if (l16 == 0) dvs[grp] = 0.f;
    {   // stage h1 row to LDS (bf16)
        uint4 o;
        o.x = pack2(a0, a1);
        o.y = pack2(a2, a3);
        o.z = pack2(a4, a5);
        o.w = pack2(a6, a7);
        *(uint4*)&lds[grp * 136 + l16 * 8] = o;
    }
    __syncthreads();
    // ---- MFMA GEMM2 epilogue: 16x128 @ 128x64; wave w computes output col-tile w ----
    const int w = threadIdx.x >> 6, lane = threadIdx.x & 63;
    const int quad = lane >> 4, m = lane & 15;
    short8 a[4];
    #pragma unroll
    for (int ks = 0; ks < 4; ++ks)
        a[ks] = *(const short8*)&lds[m * 136 + ks * 32 + quad * 8];
    float4v acc = (float4v){0.f, 0.f, 0.f, 0.f};
    const short8* wf = (const short8*)w2f;
    #pragma unroll
    for (int ks = 0; ks < 4; ++ks)
        acc = __builtin_amdgcn_mfma_f32_16x16x32_bf16(a[ks], wf[(w * 4 + ks) * 64 + lane],
                                                      acc, 0, 0, 0);
    const int node0 = blockIdx.x * 16;
    #pragma unroll
    for (int r = 0; r < 4; ++r) {
        int gn = node0 + quad * 4 + r;                // C/D: col=lane&15, row=quad*4+reg
        if (gn < N) h2[(size_t)gn * 64 + w * 16 + m] = f2b(acc[r] * dvs[quad * 4 + r]);
    }
}

// ---------------- agg layer 2: one node per 8 lanes (uint4 gathers), +b2, fp32 out ----
// h2 rows pre-scaled by dinv[src]: pure gather-sum with software-pipelined col loads.
__global__ __launch_bounds__(256) void k_agg64(const uint4* __restrict__ feat,
                                               const int2* __restrict__ begend,
                                               const int* __restrict__ col,
                                               const float* __restrict__ dinv,
                                               const float* __restrict__ bias,
                                               float* __restrict__ out, int N) {
    const int grp = threadIdx.x >> 3;                  // 32 nodes per block
    const int l8  = threadIdx.x & 7;
    const int node = blockIdx.x * 32 + grp;
    if (node >= N) return;
    const float dd = dinv[node];
    const int2 be = begend[node];
    int e = be.x; const int end = be.y;
    float a0, a1, a2, a3, a4, a5, a6, a7;
    {
        uint4 sv = feat[(size_t)node * 8 + l8];        // self-loop (pre-scaled)
        float2 q;
        q = bf2_to_f2(sv.x); a0 = q.x; a1 = q.y;
        q = bf2_to_f2(sv.y); a2 = q.x; a3 = q.y;
        q = bf2_to_f2(sv.z); a4 = q.x; a5 = q.y;
        q = bf2_to_f2(sv.w); a6 = q.x; a7 = q.y;
    }
    int c0, c1, c2, c3;
    if (e + 4 <= end) { c0 = col[e]; c1 = col[e + 1]; c2 = col[e + 2]; c3 = col[e + 3]; }
    for (; e + 8 <= end; e += 4) {                     // prefetch next quad's col indices
        int n0 = col[e + 4], n1 = col[e + 5], n2 = col[e + 6], n3 = col[e + 7];
        uint4 u0 = feat[(size_t)c0 * 8 + l8];
        uint4 u1 = feat[(size_t)c1 * 8 + l8];
        uint4 u2 = feat[(size_t)c2 * 8 + l8];
        uint4 u3 = feat[(size_t)c3 * 8 + l8];
        ACC16(u0) ACC16(u1) ACC16(u2) ACC16(u3)
        c0 = n0; c1 = n1; c2 = n2; c3 = n3;
    }
    if (e + 4 <= end) {
        uint4 u0 = feat[(size_t)c0 * 8 + l8];
        uint4 u1 = feat[(size_t)c1 * 8 + l8];
        uint4 u2 = feat[(size_t)c2 * 8 + l8];
        uint4 u3 = feat[(size_t)c3 * 8 + l8];
        ACC16(u0) ACC16(u1) ACC16(u2) ACC16(u3)
        e += 4;
    }
    for (; e < end; ++e) {
        uint4 u = feat[(size_t)col[e] * 8 + l8];
        ACC16(u)
    }
    float4 ba = ((const float4*)bias)[2 * l8];
    float4 bb = ((const float4*)bias)[2 * l8 + 1];
    float4 o1, o2;
    o1.x = a0 * dd + ba.x;
    o1.y = a1 * dd + ba.y;
    o1.z = a2 * dd + ba.z;
    o1.w = a3 * dd + ba.w;
    o2.x = a4 * dd + bb.x;
    o2.y = a5 * dd + bb.y;
    o2.z = a6 * dd + bb.z;
    o2.w = a7 * dd + bb.w;
    float4* op = (float4*)out + (size_t)node * 16 + 2 * l8;
    op[0] = o1;
    op[1] = o2;
}

extern "C" void kernel_launch(void* const* d_in, const int* in_sizes, int n_in,
                              void* d_out, int out_size, void* d_ws, size_t ws_size,
                              hipStream_t stream) {
    const float* x  = (const float*)d_in[0];
    const int*   ei = (const int*)d_in[1];
    const float* W1 = (const float*)d_in[2];
    const float* b1 = (const float*)d_in[3];
    const float* W2 = (const float*)d_in[4];
    const float* b2 = (const float*)d_in[5];

    const int N = in_sizes[0] / IN_C;               // 50000
    const int E = in_sizes[1] / 2;                  // 800000
    const int NBK  = (N + BK - 1) / BK;             // 391 buckets
    const int NCHK = (E + 2047) / 2048;             // 391 edge chunks
    const int NT1  = (N + 63) / 64;                 // 782 GEMM tiles

    char* ws = (char*)d_ws;
    int*            bfill   = (int*)(ws + 64);
    int2*           begend  = (int2*)(ws + 4096);
    float*          dinv    = (float*)(ws + 404480);
    unsigned short* w1f     = (unsigned short*)(ws + 604672);
    unsigned short* w2f     = (unsigned short*)(ws + 637440);
    int*            ebuf    = (int*)(ws + 655360);               // NBK<<CAPLG packed ints
    int*            col     = (int*)(ws + 7061504);
    unsigned short* h       = (unsigned short*)(ws + 13467904);  // bf16 [N,128], pre-scaled
    unsigned short* h2      = (unsigned short*)(ws + 26267904);  // bf16 [N,64], pre-scaled

    // ---- bfill zero (graph-capture-legal async memset) ----
    hipMemsetAsync(bfill, 0, NBK * sizeof(int), stream);

    // ---- fused: edge partition + dtype probe | weight prep ----
    k_bpart<<<NCHK + 96, 256, 0, stream>>>(ei, bfill, ebuf, E, NBK, NCHK,
                                           W1, W2, w1f, w2f);

    // ---- fused: bucket-local CSR finalize + GEMM1 (h pre-scaled via local histogram) ----
    k_blmg1<<<NBK + NT1, 256, 0, stream>>>(ebuf, bfill, begend, dinv, col,
                                           x, w1f, h, N, NBK);

    // ---- fused layer-1 aggregation (+b1, ReLU) + GEMM2 MFMA epilogue ----
    k_aggmg2<<<(N + 15) / 16, 256, 0, stream>>>((const uint4*)h, begend, col, dinv, b1,
                                                w2f, h2, N);

    // ---- layer 2 aggregation (+b2, fp32 out) ----
    k_agg64<<<(N + 31) / 32, 256, 0, stream>>>((const uint4*)h2, begend, col, dinv, b2,
                                               (float*)d_out, N);
}